// Round 11
// baseline (305.903 us; speedup 1.0000x reference)
//
#include <hip/hip_runtime.h>
#include <hip/hip_bf16.h>
#include <stdint.h>

#define B_ROWS 16384
#define K_DIM  2048   // IN + H
#define H_DIM  1024
#define N_DIM  4096   // 4*H
#define KB     (K_DIM * 2)      // bytes per packed row (4096)
#define NT     (K_DIM / 64)     // 32 K-tiles of BK=64
#define BUF0   0u
#define BUF1   65536u           // LDS double buffer: A 32K + B 32K each

using f32x4  = __attribute__((ext_vector_type(4))) float;
using bf16x8 = __attribute__((ext_vector_type(8))) __bf16;

// RNE float -> bf16 (inputs are finite)
__device__ __forceinline__ unsigned short f2bf(float f) {
    union { float f; unsigned u; } v; v.f = f;
    unsigned r = v.u + 0x7fffu + ((v.u >> 16) & 1u);
    return (unsigned short)(r >> 16);
}

// async global->LDS, 16B/lane. LDS dest must be wave-uniform (HW adds lane*16).
__device__ __forceinline__ void gload16(const void* g, const void* l) {
    __builtin_amdgcn_global_load_lds(
        (const __attribute__((address_space(1))) void*)g,
        (__attribute__((address_space(3))) void*)l,
        16, 0, 0);
}

__device__ __forceinline__ float rcp1p(float e) {   // 1/(1+e)
    return __builtin_amdgcn_rcpf(1.f + e);
}

// ---------------- pack kernels (unchanged, verified) ----------------
__global__ void pack_a_kernel(const float* __restrict__ x, const float* __restrict__ h0,
                              unsigned short* __restrict__ A) {
    int tid = blockIdx.x * 256 + threadIdx.x;
    int64_t idx = (int64_t)tid * 4;
    int b = (int)(idx >> 11);
    int k = (int)(idx & 2047);
    const float* src = (k < 1024) ? (x + (int64_t)b * 1024 + k)
                                  : (h0 + (int64_t)b * 1024 + (k - 1024));
    float4 v = *(const float4*)src;
    ushort4 o;
    o.x = f2bf(v.x); o.y = f2bf(v.y); o.z = f2bf(v.z); o.w = f2bf(v.w);
    *(ushort4*)(A + idx) = o;
}

__global__ void pack_w_kernel(const float* __restrict__ wi, const float* __restrict__ wh,
                              const float* __restrict__ bi, const float* __restrict__ bh,
                              unsigned short* __restrict__ W, float* __restrict__ bias) {
    int tid = blockIdx.x * 256 + threadIdx.x;
    int64_t idx = (int64_t)tid * 4;
    int r = (int)(idx >> 11);
    int k = (int)(idx & 2047);
    int h = r >> 2, g = r & 3;
    const float* src = (k < 1024)
        ? (wi + (int64_t)g * 1048576 + (int64_t)h * 1024 + k)
        : (wh + (int64_t)g * 1048576 + (int64_t)h * 1024 + (k - 1024));
    float4 v = *(const float4*)src;
    ushort4 o;
    o.x = f2bf(v.x); o.y = f2bf(v.y); o.z = f2bf(v.z); o.w = f2bf(v.w);
    *(ushort4*)(W + idx) = o;
    if (k == 0) bias[r] = bi[g * 1024 + h] + bh[g * 1024 + h];
}

// ------ 256x256 GEMM: parity ROLE-SPLIT waves (r9 discipline) + fused epilogue ------
// LDS buffer (x2 @ 0/65536): A kk0 @0 (16K), A kk1 @16384, B kk0 @32768, B kk1 @49152.
// Layout/swizzle/staging/read addressing/banks/LGKM counts: IDENTICAL to verified r9.
// NEW: waves split by wm (= SIMD-pairing parity; SIMD id = w&3 hosts one of each):
//   even (wm=0) phase: {RD(next-bank); STAGE; [VM2]; BAR; LGKM(n); MFMA(cur-bank)}
//   odd  (wm=1) phase: {STAGE; [VM2]; BAR; LGKM0; MFMA(cur-bank); SCHED0; RD(next-bank)}
// -> in every inter-barrier interval one wave/SIMD issues MFMA first while the other
//    issues ds_reads first: LDS pipe and MFMA pipe both fed throughout (T5 mechanism).
// Hazard ledger deltas vs r9 (re-derived):
//  - odd's reads are LATER -> RAW strictly safer (still after covering VM+BAR).
//  - WAR: odd reads region X @post(p), retired by its LGKM0 @post(p+1) < BAR(p+1);
//    earliest stage into X is @pre(p+2+) (r9 slot map) -> >=1 full barrier margin. OK
//  - odd's MFMA operands: read @post(p-1), drained by LGKM0 @post(p) after ~1 interval. OK
//  - barrier count identical per parity (4/tile) -> collective s_barrier satisfied.

#define FENCE   asm volatile("" ::: "memory")
#define BARRIER do { FENCE; __builtin_amdgcn_s_barrier(); FENCE; } while (0)
#define VM2     asm volatile("s_waitcnt vmcnt(2)" ::: "memory")
#define LGKM0   asm volatile("s_waitcnt lgkmcnt(0)" ::: "memory")
#define LGKM4   asm volatile("s_waitcnt lgkmcnt(4)" ::: "memory")
#define LGKM8   asm volatile("s_waitcnt lgkmcnt(8)" ::: "memory")
#define SCHED0  __builtin_amdgcn_sched_barrier(0)
#define SP1     __builtin_amdgcn_s_setprio(1)
#define SP0     __builtin_amdgcn_s_setprio(0)

__global__ __launch_bounds__(512, 2) void lstm_gemm_fused(
    const unsigned short* __restrict__ A, const unsigned short* __restrict__ W,
    const float* __restrict__ bias, const float* __restrict__ c0,
    float* __restrict__ ht, float* __restrict__ ct)
{
    __shared__ char sm[131072];

    const int tid = threadIdx.x;
    const int l   = tid & 63;
    const int w   = tid >> 6;         // wave 0..7
    const int wm  = w >> 2;           // 0..1  (row half AND role parity; SIMD = w&3)
    const int wn  = w & 3;            // 0..3  (col quarter: 64 cols)

    // XCD-aware bijective swizzle (1024 blocks, %8==0)
    const int bid = blockIdx.x;
    const int nid = (bid & 7) * 128 + (bid >> 3);
    const int bm  = nid >> 4;         // 0..63 (M tiles)
    const int bn  = nid & 15;         // 0..15 (N tiles)

    f32x4 acc[8][4];
#pragma unroll
    for (int i = 0; i < 8; ++i)
#pragma unroll
        for (int j = 0; j < 4; ++j) acc[i][j] = (f32x4){0.f, 0.f, 0.f, 0.f};

    // ---- staging source addressing (inverse-swizzled), pointer-bumped per tile ----
    const int srow = w * 16 + (l >> 2);                 // 0..127
    const int scb  = ((l & 3) << 4) ^ (l & 32);
    const char* Asrc = (const char*)A + (size_t)(bm * 256 + srow) * KB + scb;
    const char* Wsrc = (const char*)W + (size_t)(bn * 256 + srow) * KB + scb;
    const uint32_t wL = (uint32_t)w * 1024u;            // wave-uniform LDS dest part

#define STAGE_A(KK, BOFF) do { \
    gload16(Asrc + (KK) * 64,            sm + (BOFF) + (KK) * 16384u + wL); \
    gload16(Asrc + (KK) * 64 + 128 * KB, sm + (BOFF) + (KK) * 16384u + 8192u + wL); \
} while (0)
#define STAGE_B(KK, BOFF) do { \
    gload16(Wsrc + (KK) * 64,            sm + (BOFF) + 32768u + (KK) * 16384u + wL); \
    gload16(Wsrc + (KK) * 64 + 128 * KB, sm + (BOFF) + 32768u + (KK) * 16384u + 8192u + wL); \
} while (0)
#define BUMP do { Asrc += 128; Wsrc += 128; } while (0)

    // ---- fragment read addressing (swizzled, r5-verified) ----
    const int rr = l & 15, kg = l >> 4;
    const uint32_t loff = (uint32_t)rr * 64u + (((uint32_t)kg * 16u) ^ (uint32_t)((rr & 8) << 2));
    const uint32_t Ard = (uint32_t)wm * 8192u + loff;             // + BOFF + KK*16384 + mf*1024
    const uint32_t Brd = 32768u + (uint32_t)wn * 4096u + loff;    // + BOFF + KK*16384 + nf*1024

    bf16x8 aL0[4], aH0[4], aL1[4], aH1[4], bb0[4], bb1[4];

#define RD_A4(BOFF, KK, MB, ARR) do { \
    _Pragma("unroll") \
    for (int i_ = 0; i_ < 4; ++i_) \
        ARR[i_] = *(const bf16x8*)(sm + (BOFF) + (KK) * 16384u + Ard + ((MB) + i_) * 1024u); \
} while (0)
#define RD_B4(BOFF, KK, BRR) do { \
    _Pragma("unroll") \
    for (int i_ = 0; i_ < 4; ++i_) \
        BRR[i_] = *(const bf16x8*)(sm + (BOFF) + (KK) * 16384u + Brd + i_ * 1024u); \
} while (0)

#define MFMA16H(ARR, MB, BRR) do { \
    _Pragma("unroll") \
    for (int mf_ = 0; mf_ < 4; ++mf_) \
        _Pragma("unroll") \
        for (int nf_ = 0; nf_ < 4; ++nf_) \
            acc[(MB) + mf_][nf_] = __builtin_amdgcn_mfma_f32_16x16x32_bf16( \
                ARR[mf_], BRR[nf_], acc[(MB) + mf_][nf_], 0, 0, 0); \
} while (0)

    // ---- prologue: stage tile0; drain kk0 (kk1's 4 stay in flight);
    //      pre-read first MFMA operands (both parities) ----
    STAGE_A(0, BUF0); STAGE_B(0, BUF0);   // kk0 t0 (4)
    STAGE_A(1, BUF0); STAGE_B(1, BUF0);   // kk1 t0 (4)
    BUMP;                                 // ptr -> t1
    asm volatile("s_waitcnt vmcnt(4)" ::: "memory");
    BARRIER;
    RD_A4(BUF0, 0, 0, aL0); RD_B4(BUF0, 0, bb0);   // 8 reads outstanding

    // ---- even (wm=0) tile body: r9 verbatim ----
#define DO_TILE_E(CUR, NXT) do { \
    RD_A4(CUR, 0, 4, aH0); \
    STAGE_A(0, NXT); \
    VM2; BARRIER; LGKM4; SP1; MFMA16H(aL0, 0, bb0); SP0; \
    RD_A4(CUR, 1, 0, aL1); RD_B4(CUR, 1, bb1); \
    STAGE_B(0, NXT); \
    BARRIER; LGKM8; SP1; MFMA16H(aH0, 4, bb0); SP0; \
    RD_A4(CUR, 1, 4, aH1); \
    STAGE_A(1, NXT); \
    VM2; BARRIER; LGKM4; SP1; MFMA16H(aL1, 0, bb1); SP0; \
    RD_A4(NXT, 0, 0, aL0); RD_B4(NXT, 0, bb0); \
    STAGE_B(1, NXT); \
    BUMP; \
    BARRIER; LGKM8; SP1; MFMA16H(aH1, 4, bb1); SP0; \
} while (0)

    // ---- odd (wm=1) tile body: MFMA-first, reads post-cluster (role-split) ----
#define DO_TILE_O(CUR, NXT) do { \
    STAGE_A(0, NXT); \
    VM2; BARRIER; LGKM0; SP1; MFMA16H(aL0, 0, bb0); SP0; SCHED0; \
    RD_A4(CUR, 0, 4, aH0); \
    STAGE_B(0, NXT); \
    BARRIER; LGKM0; SP1; MFMA16H(aH0, 4, bb0); SP0; SCHED0; \
    RD_A4(CUR, 1, 0, aL1); RD_B4(CUR, 1, bb1); \
    STAGE_A(1, NXT); \
    VM2; BARRIER; LGKM0; SP1; MFMA16H(aL1, 0, bb1); SP0; SCHED0; \
    RD_A4(CUR, 1, 4, aH1); \
    STAGE_B(1, NXT); \
    BUMP; \
    BARRIER; LGKM0; SP1; MFMA16H(aH1, 4, bb1); SP0; SCHED0; \
    RD_A4(NXT, 0, 0, aL0); RD_B4(NXT, 0, bb0); \
} while (0)

    if (wm == 0) {
#pragma unroll 1
        for (int tt = 0; tt < NT; tt += 2) {
            DO_TILE_E(BUF0, BUF1);
            DO_TILE_E(BUF1, BUF0);
        }
    } else {
#pragma unroll 1
        for (int tt = 0; tt < NT; tt += 2) {
            DO_TILE_O(BUF0, BUF1);
            DO_TILE_O(BUF1, BUF0);
        }
    }
    // (final tile's last reads are t32 garbage into aL0/bb0 -- never consumed;
    //  its stages land in BUF1 -- never read. Sources stay inside d_ws.)

    // ---- fused LSTM epilogue (r5-verified) ----
    asm volatile("s_waitcnt vmcnt(0) lgkmcnt(0)" ::: "memory");
    BARRIER;

    float* ep = (float*)(void*)sm + w * 1088;   // 16 rows x 68 floats per wave
    const int hbase = bn * 64 + wn * 16;
    const int rbase = bm * 256 + wm * 128;

#pragma unroll
    for (int mf = 0; mf < 8; ++mf) {
        // scatter acc slice (16 rows x 64 cols) to LDS, padded stride 68
#pragma unroll
        for (int nf = 0; nf < 4; ++nf)
#pragma unroll
            for (int r = 0; r < 4; ++r)
                ep[((l >> 4) * 4 + r) * 68 + nf * 16 + (l & 15)] = acc[mf][nf][r];

        // gather: lane -> (row, h); cols 4h..4h+3 = gates f,i,o,g
#pragma unroll
        for (int it = 0; it < 4; ++it) {
            const int row = (l >> 4) + it * 4;
            const int hs  = l & 15;
            f32x4 z = *(const f32x4*)(ep + row * 68 + hs * 4);
            const int hg = hbase + hs;
            const float4 bz = ((const float4*)bias)[hg];
            const int brow = rbase + mf * 16 + row;

            float zf = z.x + bz.x;
            float zi = z.y + bz.y;
            float zo = z.z + bz.z;
            float zg = z.w + bz.w;

            float fg = rcp1p(__expf(-zf));                   // sigmoid
            float ig = rcp1p(__expf(-zi));
            float og = rcp1p(__expf(-zo));
            float gg = 2.f * rcp1p(__expf(-2.f * zg)) - 1.f; // tanh

            int64_t oi = (int64_t)brow * H_DIM + hg;
            float c  = fg * c0[oi] + ig * gg;
            float hh = og * (2.f * rcp1p(__expf(-2.f * c)) - 1.f);
            ct[oi] = c;
            ht[oi] = hh;
        }
    }
}

extern "C" void kernel_launch(void* const* d_in, const int* in_sizes, int n_in,
                              void* d_out, int out_size, void* d_ws, size_t ws_size,
                              hipStream_t stream) {
    const float* x  = (const float*)d_in[0];
    const float* h0 = (const float*)d_in[1];
    const float* c0 = (const float*)d_in[2];
    const float* wi = (const float*)d_in[3];
    const float* bi = (const float*)d_in[4];
    const float* wh = (const float*)d_in[5];
    const float* bh = (const float*)d_in[6];

    float* ht = (float*)d_out;
    float* ct = ht + (int64_t)B_ROWS * H_DIM;

    char* ws = (char*)d_ws;
    unsigned short* A  = (unsigned short*)ws;                       // 64 MiB
    unsigned short* Wp = (unsigned short*)(ws + (64u << 20));       // 16 MiB
    float*          bs = (float*)(ws + (80u << 20));                // 16 KiB

    pack_a_kernel<<<32768, 256, 0, stream>>>(x, h0, A);
    pack_w_kernel<<<8192, 256, 0, stream>>>(wi, wh, bi, bh, Wp, bs);

    lstm_gemm_fused<<<1024, 512, 0, stream>>>(A, Wp, bs, c0, ht, ct);
}